// Round 2
// baseline (527.898 us; speedup 1.0000x reference)
//
#include <hip/hip_runtime.h>
#include <hip/hip_cooperative_groups.h>
#include <math.h>

namespace cg = cooperative_groups;

#define BB 16
#define NN 8192
#define DD 128
#define CC 64
#define ROWS (BB*NN)            // 131072
#define INV_TEMP (1.0f/6.0f)    // temp = 2*(1+192/96) = 6
#define NEGF (-3.402823e38f)
#define LDSS 132                // k_ortho LDS row stride (fallback)

#define RPB 128                 // rows per block
#define CHW 32                  // chunk width (floats of j)
#define XST 34                  // LDS row stride in dwords (2-way conflict max, 8B aligned)

__device__ __forceinline__ unsigned f2bf(float f) {
    unsigned u = __builtin_bit_cast(unsigned, f);
    return (u + 0x7fffu + ((u >> 16) & 1u)) >> 16;   // RNE
}
__device__ __forceinline__ float bflo(unsigned u) { return __builtin_bit_cast(float, u << 16); }
__device__ __forceinline__ float bfhi(unsigned u) { return __builtin_bit_cast(float, u & 0xffff0000u); }

// ===========================================================================
// k_fused: whole pipeline in one cooperative launch.
// grid = 1024 = 256 CU x 4 blocks/CU (launch_bounds(256,4), LDS 22.8 KB).
// A: scores/softmax/top4, q kept in f32 regs, colpart per block (no qbuf!)
// sync; B: blk0 colsum reduce | blks 64..79 ortho; sync; C: KL from regs;
// sync; blk0 aux; D: barrier-free streaming xc/xr epilogue.
// ===========================================================================
__global__ __launch_bounds__(256, 4) void k_fused(
    const float* __restrict__ x, const float* __restrict__ dict,
    float* __restrict__ xcg, float* __restrict__ xrg,
    float* __restrict__ colpart, float* __restrict__ colsum,
    float* __restrict__ klacc, float* __restrict__ oacc,
    float* __restrict__ aux)
{
    __shared__ __align__(16) float bufA[RPB * XST];   // 17408 B: x stage, t4 exch, q bf16, rF/lF/kred, cred
    __shared__ float red2[RPB][2];
    __shared__ float colsumA[CC];
    __shared__ __align__(16) float w4s[RPB][4];       // top-4 softmax weights per row
    __shared__ __align__(16) int   si4s[RPB][4];      // top-4 indices per row

    cg::grid_group gg = cg::this_grid();

    const int tid   = threadIdx.x;
    const int rloc  = tid & (RPB - 1);
    const int chalf = tid >> 7;
    const int cbase = __builtin_amdgcn_readfirstlane(chalf << 5);  // wave-uniform -> s_load
    const int bid   = blockIdx.x;
    const int row0  = bid * RPB;

    if (bid == 0 && tid == 0) { klacc[0] = 0.f; oacc[0] = 0.f; }   // idempotent per replay
    if (tid < CC) colsumA[tid] = 0.f;

    const int sr = tid >> 3;            // staging row 0..31 (+32p)
    const int sj = (tid & 7) * 4;       // staging j offset
    const float* xstage = x + (size_t)(row0 + sr) * DD + sj;

    float s[32];
#pragma unroll
    for (int cc = 0; cc < 32; ++cc) s[cc] = 0.f;

    // ---------------- phase A1: scores, software-pipelined staging ---------
    float4 rp[4];
#pragma unroll
    for (int p = 0; p < 4; ++p)
        rp[p] = *(const float4*)(xstage + (size_t)p * 32 * DD);
#pragma unroll
    for (int p = 0; p < 4; ++p) {
        float* dst = &bufA[XST * (sr + 32 * p) + sj];
        *(float2*)dst       = make_float2(rp[p].x, rp[p].y);
        *(float2*)(dst + 2) = make_float2(rp[p].z, rp[p].w);
    }
    __syncthreads();

    for (int ch = 0; ch < 4; ++ch) {
        const int j0 = ch * CHW;
        if (ch < 3) {   // issue next chunk's loads; latency hides under compute
#pragma unroll
            for (int p = 0; p < 4; ++p)
                rp[p] = *(const float4*)(xstage + (size_t)p * 32 * DD + (j0 + CHW));
        }
        const float* xrow = &bufA[XST * rloc];
        for (int js = 0; js < CHW; js += 4) {
            const float2 x01 = *(const float2*)(xrow + js);
            const float2 x23 = *(const float2*)(xrow + js + 2);
            const float* dcol = dict + (size_t)cbase * DD + (j0 + js);
#pragma unroll
            for (int cc = 0; cc < 32; ++cc) {
                const float* dp = dcol + cc * DD;   // uniform address -> s_load
                float acc = s[cc];
                acc = fmaf(x01.x, dp[0], acc);
                acc = fmaf(x01.y, dp[1], acc);
                acc = fmaf(x23.x, dp[2], acc);
                acc = fmaf(x23.y, dp[3], acc);
                s[cc] = acc;
            }
        }
        if (ch < 3) {
            __syncthreads();   // all consumers of bufA done
#pragma unroll
            for (int p = 0; p < 4; ++p) {
                float* dst = &bufA[XST * (sr + 32 * p) + sj];
                *(float2*)dst       = make_float2(rp[p].x, rp[p].y);
                *(float2*)(dst + 2) = make_float2(rp[p].z, rp[p].w);
            }
            __syncthreads();
        }
    }

    // ---------------- phase A2: max across the pair ----------------
    float lm = s[0];
#pragma unroll
    for (int cc = 1; cc < 32; ++cc) lm = fmaxf(lm, s[cc]);
    red2[rloc][chalf] = lm;
    __syncthreads();
    const float mg = fmaxf(red2[rloc][0], red2[rloc][1]);
    __syncthreads();

    // ---------------- top-4 local on RAW s (strict '>' => lowest index) ----
    float tv[4]; int ti[4];
    {
        float best = NEGF; int bi = 0;
#pragma unroll
        for (int cc = 0; cc < 32; ++cc) { if (s[cc] > best) { best = s[cc]; bi = cc; } }
        tv[0] = best; ti[0] = bi;
    }
    {
        float best = NEGF; int bi = 0;
#pragma unroll
        for (int cc = 0; cc < 32; ++cc) {
            const float v = (cc == ti[0]) ? NEGF : s[cc];
            if (v > best) { best = v; bi = cc; }
        }
        tv[1] = best; ti[1] = bi;
    }
    {
        float best = NEGF; int bi = 0;
#pragma unroll
        for (int cc = 0; cc < 32; ++cc) {
            const float v = (cc == ti[0] || cc == ti[1]) ? NEGF : s[cc];
            if (v > best) { best = v; bi = cc; }
        }
        tv[2] = best; ti[2] = bi;
    }
    {
        float best = NEGF; int bi = 0;
#pragma unroll
        for (int cc = 0; cc < 32; ++cc) {
            const float v = (cc == ti[0] || cc == ti[1] || cc == ti[2]) ? NEGF : s[cc];
            if (v > best) { best = v; bi = cc; }
        }
        tv[3] = best; ti[3] = bi;
    }

    // ---------------- single exp pass: s -> e, then normalize to q ---------
    float lz = 0.f;
#pragma unroll
    for (int cc = 0; cc < 32; ++cc) {
        const float e = __expf((s[cc] - mg) * INV_TEMP);
        s[cc] = e; lz += e;
    }
    red2[rloc][chalf] = lz;
    __syncthreads();
    const float rZ = 1.f / (red2[rloc][0] + red2[rloc][1]);
#pragma unroll
    for (int cc = 0; cc < 32; ++cc) s[cc] *= rZ;     // s[] is now q (f32), stays live thru phase C

    // ---------------- top-4 merge across the pair (via LDS) ---------------
    float* t4v = bufA;
    int*   t4i = (int*)(bufA + 1024);
    {
        const int b4 = (rloc * 2 + chalf) * 4;
#pragma unroll
        for (int k = 0; k < 4; ++k) { t4v[b4 + k] = tv[k]; t4i[b4 + k] = cbase + ti[k]; }
    }
    __syncthreads();
    float cv[8]; int ci[8];
#pragma unroll
    for (int h = 0; h < 2; ++h) {
#pragma unroll
        for (int k = 0; k < 4; ++k) {
            cv[h * 4 + k] = t4v[(rloc * 2 + h) * 4 + k];
            ci[h * 4 + k] = t4i[(rloc * 2 + h) * 4 + k];
        }
    }
    __syncthreads();   // bufA free for reuse after this

    int rank[8];
#pragma unroll
    for (int j = 0; j < 8; ++j) rank[j] = 0;
#pragma unroll
    for (int j = 0; j < 8; ++j) {
#pragma unroll
        for (int k = 0; k < 8; ++k) {
            if (k == j) continue;
            const bool kg = (cv[k] > cv[j]) || (cv[k] == cv[j] && ci[k] < ci[j]);
            rank[j] += kg ? 1 : 0;
        }
    }
    float sv[4]; int si[4];
#pragma unroll
    for (int t2 = 0; t2 < 4; ++t2) { sv[t2] = NEGF; si[t2] = 0; }
#pragma unroll
    for (int j = 0; j < 8; ++j) {
#pragma unroll
        for (int t2 = 0; t2 < 4; ++t2) {
            const bool sel = (rank[j] == t2);
            sv[t2] = sel ? cv[j] : sv[t2];
            si[t2] = sel ? ci[j] : si[t2];
        }
    }
    const float e1 = __expf((sv[1] - sv[0]) * INV_TEMP);
    const float e2 = __expf((sv[2] - sv[0]) * INV_TEMP);
    const float e3 = __expf((sv[3] - sv[0]) * INV_TEMP);
    const float rZ4 = 1.f / (1.f + e1 + e2 + e3);
    const float w0 = rZ4, w1 = e1 * rZ4, w2 = e2 * rZ4, w3 = e3 * rZ4;

    if (chalf == 0) {
        *(float4*)&w4s[rloc][0] = make_float4(w0, w1, w2, w3);
        *(int4*)&si4s[rloc][0]  = make_int4(si[0], si[1], si[2], si[3]);
    }

    // ---------------- q -> LDS (bf16) for conflict-free colsum only --------
    {
        unsigned* qs = (unsigned*)bufA;
        const int base = XST * rloc + 16 * chalf;
#pragma unroll
        for (int k2 = 0; k2 < 16; k2 += 2) {
            uint2 w;
            w.x = (f2bf(s[2 * k2 + 1]) << 16) | f2bf(s[2 * k2 + 0]);
            w.y = (f2bf(s[2 * k2 + 3]) << 16) | f2bf(s[2 * k2 + 2]);
            *(uint2*)&qs[base + k2] = w;
        }
        __syncthreads();
        const int cp  = tid & 31;
        const int rr0 = (tid >> 5) * 16;
        float c0 = 0.f, c1 = 0.f;
#pragma unroll
        for (int rr = 0; rr < 16; ++rr) {
            const unsigned u = qs[XST * (rr0 + rr) + cp];
            c0 += bflo(u); c1 += bfhi(u);
        }
        atomicAdd(&colsumA[2 * cp + 0], c0);   // 8-way only
        atomicAdd(&colsumA[2 * cp + 1], c1);
    }
    __syncthreads();
    if (tid < CC) colpart[bid * CC + tid] = colsumA[tid];

    gg.sync();   // ---- grid sync #1: colpart visible ----

    // ---------------- phase B: colsum reduce (blk 0) | ortho (blks 64..79) -
    if (bid == 0) {
        const int c = tid & 63, qt = tid >> 6;
        float v = 0.f;
#pragma unroll 8
        for (int i = 0; i < 256; ++i)
            v += colpart[(size_t)(((qt << 8) + i) * 64 + c)];   // coalesced
        float* cred = bufA;
        cred[tid] = v;
        __syncthreads();
        if (tid < CC)
            colsum[tid] = cred[tid] + cred[tid + 64] + cred[tid + 128] + cred[tid + 192];
    } else if (bid >= 64 && bid < 80) {
        const int e = (bid - 64) * 256 + tid;   // [0,4096)
        const int i = e >> 6, jj = e & 63;
        const float* di = dict + (size_t)i * DD;
        const float* dj = dict + (size_t)jj * DD;
        float g = 0.f;
#pragma unroll 8
        for (int d = 0; d < DD; d += 4) {
            const float4 a = *(const float4*)(di + d);
            const float4 b = *(const float4*)(dj + d);
            g += a.x * b.x + a.y * b.y + a.z * b.z + a.w * b.w;
        }
        const float diff = g - ((i == jj) ? 1.f : 0.f);
        float v = diff * diff;
#pragma unroll
        for (int off = 32; off > 0; off >>= 1)
            v += __shfl_down(v, off, 64);
        if ((tid & 63) == 0) atomicAdd(oacc, v);
    }

    gg.sync();   // ---- grid sync #2: colsum/oacc visible ----

    // ---------------- phase C: KL from f32 q in registers ------------------
    {
        float* rF   = bufA;         // 64
        float* lF   = bufA + 64;    // 64
        float* kred = bufA + 128;   // 4
        if (tid < CC) { const float F = colsum[tid]; rF[tid] = 1.f / F; lF[tid] = __logf(F); }
        __syncthreads();
        float Sh = 0.f;
#pragma unroll
        for (int cc = 0; cc < 32; ++cc) Sh = fmaf(s[cc] * s[cc], rF[cbase + cc], Sh);
        red2[rloc][chalf] = Sh;
        __syncthreads();
        const float Sr = red2[rloc][0] + red2[rloc][1];
        const float rS = 1.f / Sr;
        const float lS = __logf(Sr);
        float acc = 0.f;
#pragma unroll
        for (int cc = 0; cc < 32; ++cc) {
            const float q = s[cc];
            const float p = q * q * rF[cbase + cc] * rS;
            acc += p * (__logf(q) - lF[cbase + cc] - lS);
        }
#pragma unroll
        for (int off = 32; off > 0; off >>= 1) acc += __shfl_down(acc, off, 64);
        if ((tid & 63) == 0) kred[tid >> 6] = acc;
        __syncthreads();
        if (tid == 0) atomicAdd(klacc, kred[0] + kred[1] + kred[2] + kred[3]);
    }

    gg.sync();   // ---- grid sync #3: klacc/oacc final ----

    if (bid == 0 && tid == 0)
        aux[0] = 0.5f * (klacc[0] / (float)ROWS) + 0.1f * (oacc[0] / 4096.f);

    // ---------------- phase D: barrier-free streaming epilogue -------------
#pragma unroll 2
    for (int it = 0; it < 16; ++it) {
        const int gd  = it * 1024 + tid * 4;
        const int row = gd >> 7;
        const int dd  = gd & 127;
        const float4 wv = *(const float4*)&w4s[row][0];
        const int4  iv  = *(const int4*)&si4s[row][0];
        const size_t go = (size_t)(row0 + row) * DD + dd;
        const float4 xv = *(const float4*)(x + go);
        const float4 d0 = *(const float4*)(dict + (size_t)iv.x * DD + dd);
        const float4 d1 = *(const float4*)(dict + (size_t)iv.y * DD + dd);
        const float4 d2 = *(const float4*)(dict + (size_t)iv.z * DD + dd);
        const float4 d3 = *(const float4*)(dict + (size_t)iv.w * DD + dd);
        float4 c4, r4;
        c4.x = fmaf(wv.w, d3.x, fmaf(wv.z, d2.x, fmaf(wv.y, d1.x, wv.x * d0.x)));
        c4.y = fmaf(wv.w, d3.y, fmaf(wv.z, d2.y, fmaf(wv.y, d1.y, wv.x * d0.y)));
        c4.z = fmaf(wv.w, d3.z, fmaf(wv.z, d2.z, fmaf(wv.y, d1.z, wv.x * d0.z)));
        c4.w = fmaf(wv.w, d3.w, fmaf(wv.z, d2.w, fmaf(wv.y, d1.w, wv.x * d0.w)));
        r4.x = xv.x - c4.x; r4.y = xv.y - c4.y;
        r4.z = xv.z - c4.z; r4.w = xv.w - c4.w;
        *(float4*)(xcg + go) = c4;
        *(float4*)(xrg + go) = r4;
    }
}

// ===========================================================================
// Fallback pipeline (round-1, proven) — used only if cooperative launch fails
// ===========================================================================
__global__ __launch_bounds__(256, 4) void k_main(
    const float* __restrict__ x, const float* __restrict__ dict,
    float* __restrict__ xcg, float* __restrict__ xrg,
    unsigned* __restrict__ qg, float* __restrict__ colpart)
{
    __shared__ __align__(16) float bufA[RPB * XST];
    __shared__ float red2[RPB][2];
    __shared__ float colsumA[CC];
    __shared__ __align__(16) float w4s[RPB][4];
    __shared__ __align__(16) int   si4s[RPB][4];

    const int tid   = threadIdx.x;
    const int rloc  = tid & (RPB - 1);
    const int chalf = tid >> 7;
    const int cbase = __builtin_amdgcn_readfirstlane(chalf << 5);
    const int row0  = blockIdx.x * RPB;

    if (tid < CC) colsumA[tid] = 0.f;

    const int sr = tid >> 3;
    const int sj = (tid & 7) * 4;
    const float* xstage = x + (size_t)(row0 + sr) * DD + sj;

    float s[32];
#pragma unroll
    for (int cc = 0; cc < 32; ++cc) s[cc] = 0.f;

    float4 rp[4];
#pragma unroll
    for (int p = 0; p < 4; ++p)
        rp[p] = *(const float4*)(xstage + (size_t)p * 32 * DD);
#pragma unroll
    for (int p = 0; p < 4; ++p) {
        float* dst = &bufA[XST * (sr + 32 * p) + sj];
        *(float2*)dst       = make_float2(rp[p].x, rp[p].y);
        *(float2*)(dst + 2) = make_float2(rp[p].z, rp[p].w);
    }
    __syncthreads();

    for (int ch = 0; ch < 4; ++ch) {
        const int j0 = ch * CHW;
        if (ch < 3) {
#pragma unroll
            for (int p = 0; p < 4; ++p)
                rp[p] = *(const float4*)(xstage + (size_t)p * 32 * DD + (j0 + CHW));
        }
        const float* xrow = &bufA[XST * rloc];
        for (int js = 0; js < CHW; js += 4) {
            const float2 x01 = *(const float2*)(xrow + js);
            const float2 x23 = *(const float2*)(xrow + js + 2);
            const float* dcol = dict + (size_t)cbase * DD + (j0 + js);
#pragma unroll
            for (int cc = 0; cc < 32; ++cc) {
                const float* dp = dcol + cc * DD;
                float acc = s[cc];
                acc = fmaf(x01.x, dp[0], acc);
                acc = fmaf(x01.y, dp[1], acc);
                acc = fmaf(x23.x, dp[2], acc);
                acc = fmaf(x23.y, dp[3], acc);
                s[cc] = acc;
            }
        }
        if (ch < 3) {
            __syncthreads();
#pragma unroll
            for (int p = 0; p < 4; ++p) {
                float* dst = &bufA[XST * (sr + 32 * p) + sj];
                *(float2*)dst       = make_float2(rp[p].x, rp[p].y);
                *(float2*)(dst + 2) = make_float2(rp[p].z, rp[p].w);
            }
            __syncthreads();
        }
    }

    float lm = s[0];
#pragma unroll
    for (int cc = 1; cc < 32; ++cc) lm = fmaxf(lm, s[cc]);
    red2[rloc][chalf] = lm;
    __syncthreads();
    const float mg = fmaxf(red2[rloc][0], red2[rloc][1]);
    __syncthreads();

    float tv[4]; int ti[4];
    {
        float best = NEGF; int bi = 0;
#pragma unroll
        for (int cc = 0; cc < 32; ++cc) { if (s[cc] > best) { best = s[cc]; bi = cc; } }
        tv[0] = best; ti[0] = bi;
    }
    {
        float best = NEGF; int bi = 0;
#pragma unroll
        for (int cc = 0; cc < 32; ++cc) {
            const float v = (cc == ti[0]) ? NEGF : s[cc];
            if (v > best) { best = v; bi = cc; }
        }
        tv[1] = best; ti[1] = bi;
    }
    {
        float best = NEGF; int bi = 0;
#pragma unroll
        for (int cc = 0; cc < 32; ++cc) {
            const float v = (cc == ti[0] || cc == ti[1]) ? NEGF : s[cc];
            if (v > best) { best = v; bi = cc; }
        }
        tv[2] = best; ti[2] = bi;
    }
    {
        float best = NEGF; int bi = 0;
#pragma unroll
        for (int cc = 0; cc < 32; ++cc) {
            const float v = (cc == ti[0] || cc == ti[1] || cc == ti[2]) ? NEGF : s[cc];
            if (v > best) { best = v; bi = cc; }
        }
        tv[3] = best; ti[3] = bi;
    }

    float lz = 0.f;
#pragma unroll
    for (int cc = 0; cc < 32; ++cc) {
        const float e = __expf((s[cc] - mg) * INV_TEMP);
        s[cc] = e; lz += e;
    }
    red2[rloc][chalf] = lz;
    __syncthreads();
    const float rZ = 1.f / (red2[rloc][0] + red2[rloc][1]);
#pragma unroll
    for (int cc = 0; cc < 32; ++cc) s[cc] *= rZ;

    float* t4v = bufA;
    int*   t4i = (int*)(bufA + 1024);
    {
        const int b4 = (rloc * 2 + chalf) * 4;
#pragma unroll
        for (int k = 0; k < 4; ++k) { t4v[b4 + k] = tv[k]; t4i[b4 + k] = cbase + ti[k]; }
    }
    __syncthreads();
    float cv[8]; int ci[8];
#pragma unroll
    for (int h = 0; h < 2; ++h) {
#pragma unroll
        for (int k = 0; k < 4; ++k) {
            cv[h * 4 + k] = t4v[(rloc * 2 + h) * 4 + k];
            ci[h * 4 + k] = t4i[(rloc * 2 + h) * 4 + k];
        }
    }
    __syncthreads();

    int rank[8];
#pragma unroll
    for (int j = 0; j < 8; ++j) rank[j] = 0;
#pragma unroll
    for (int j = 0; j < 8; ++j) {
#pragma unroll
        for (int k = 0; k < 8; ++k) {
            if (k == j) continue;
            const bool kg = (cv[k] > cv[j]) || (cv[k] == cv[j] && ci[k] < ci[j]);
            rank[j] += kg ? 1 : 0;
        }
    }
    float sv[4]; int si[4];
#pragma unroll
    for (int t2 = 0; t2 < 4; ++t2) { sv[t2] = NEGF; si[t2] = 0; }
#pragma unroll
    for (int j = 0; j < 8; ++j) {
#pragma unroll
        for (int t2 = 0; t2 < 4; ++t2) {
            const bool sel = (rank[j] == t2);
            sv[t2] = sel ? cv[j] : sv[t2];
            si[t2] = sel ? ci[j] : si[t2];
        }
    }
    const float e1 = __expf((sv[1] - sv[0]) * INV_TEMP);
    const float e2 = __expf((sv[2] - sv[0]) * INV_TEMP);
    const float e3 = __expf((sv[3] - sv[0]) * INV_TEMP);
    const float rZ4 = 1.f / (1.f + e1 + e2 + e3);
    const float w0 = rZ4, w1 = e1 * rZ4, w2 = e2 * rZ4, w3 = e3 * rZ4;

    if (chalf == 0) {
        *(float4*)&w4s[rloc][0] = make_float4(w0, w1, w2, w3);
        *(int4*)&si4s[rloc][0]  = make_int4(si[0], si[1], si[2], si[3]);
    }

    {
        unsigned* qs = (unsigned*)bufA;
        const int base = XST * rloc + 16 * chalf;
#pragma unroll
        for (int k2 = 0; k2 < 16; k2 += 2) {
            uint2 w;
            w.x = (f2bf(s[2 * k2 + 1]) << 16) | f2bf(s[2 * k2 + 0]);
            w.y = (f2bf(s[2 * k2 + 3]) << 16) | f2bf(s[2 * k2 + 2]);
            *(uint2*)&qs[base + k2] = w;
        }
        __syncthreads();
        unsigned* qdst = qg + (size_t)blockIdx.x * (RPB * 32);
#pragma unroll
        for (int k4 = 0; k4 < 4; ++k4) {
            const int gd  = k4 * 1024 + tid * 4;
            const int row = gd >> 5, kk = gd & 31;
            const uint2 a = *(const uint2*)&qs[XST * row + kk];
            const uint2 b = *(const uint2*)&qs[XST * row + kk + 2];
            uint4 o; o.x = a.x; o.y = a.y; o.z = b.x; o.w = b.y;
            *(uint4*)&qdst[gd] = o;
        }
        const int cp  = tid & 31;
        const int rr0 = (tid >> 5) * 16;
        float c0 = 0.f, c1 = 0.f;
#pragma unroll
        for (int rr = 0; rr < 16; ++rr) {
            const unsigned u = qs[XST * (rr0 + rr) + cp];
            c0 += bflo(u); c1 += bfhi(u);
        }
        atomicAdd(&colsumA[2 * cp + 0], c0);
        atomicAdd(&colsumA[2 * cp + 1], c1);
    }
    __syncthreads();
    if (tid < CC) colpart[blockIdx.x * CC + tid] = colsumA[tid];

#pragma unroll 2
    for (int it = 0; it < 16; ++it) {
        const int gd  = it * 1024 + tid * 4;
        const int row = gd >> 7;
        const int dd  = gd & 127;
        const float4 wv = *(const float4*)&w4s[row][0];
        const int4  iv  = *(const int4*)&si4s[row][0];
        const size_t go = (size_t)(row0 + row) * DD + dd;
        const float4 xv = *(const float4*)(x + go);
        const float4 d0 = *(const float4*)(dict + (size_t)iv.x * DD + dd);
        const float4 d1 = *(const float4*)(dict + (size_t)iv.y * DD + dd);
        const float4 d2 = *(const float4*)(dict + (size_t)iv.z * DD + dd);
        const float4 d3 = *(const float4*)(dict + (size_t)iv.w * DD + dd);
        float4 c4, r4;
        c4.x = fmaf(wv.w, d3.x, fmaf(wv.z, d2.x, fmaf(wv.y, d1.x, wv.x * d0.x)));
        c4.y = fmaf(wv.w, d3.y, fmaf(wv.z, d2.y, fmaf(wv.y, d1.y, wv.x * d0.y)));
        c4.z = fmaf(wv.w, d3.z, fmaf(wv.z, d2.z, fmaf(wv.y, d1.z, wv.x * d0.z)));
        c4.w = fmaf(wv.w, d3.w, fmaf(wv.z, d2.w, fmaf(wv.y, d1.w, wv.x * d0.w)));
        r4.x = xv.x - c4.x; r4.y = xv.y - c4.y;
        r4.z = xv.z - c4.z; r4.w = xv.w - c4.w;
        *(float4*)(xcg + go) = c4;
        *(float4*)(xrg + go) = r4;
    }
}

__global__ void k_colsum(const float* __restrict__ colpart, float* __restrict__ colsum)
{
    const int tid = threadIdx.x;
    const int c   = tid & 63;
    const int seg = blockIdx.x * 4 + (tid >> 6);
    float v = 0.f;
#pragma unroll
    for (int b = 0; b < 16; ++b)
        v += colpart[(seg * 16 + b) * 64 + c];
    atomicAdd(&colsum[c], v);
}

__global__ __launch_bounds__(256, 2) void k_kl(
    const unsigned* __restrict__ qg, const float* __restrict__ colsum,
    float* __restrict__ klacc)
{
    __shared__ __align__(8) unsigned qs[256 * XST];
    __shared__ float rF[CC], lF[CC];
    __shared__ float kred[4];
    const int tid = threadIdx.x;
    if (tid < CC) { const float F = colsum[tid]; rF[tid] = 1.f / F; lF[tid] = __logf(F); }
    const unsigned* qb = qg + (size_t)blockIdx.x * 8192;
#pragma unroll
    for (int g = 0; g < 8; ++g) {
        const int gd = g * 1024 + tid * 4;
        const uint4 v = *(const uint4*)(qb + gd);
        const int row = gd >> 5, kk = gd & 31;
        *(uint2*)&qs[XST * row + kk]     = make_uint2(v.x, v.y);
        *(uint2*)&qs[XST * row + kk + 2] = make_uint2(v.z, v.w);
    }
    __syncthreads();
    const unsigned* qr = &qs[XST * tid];
    unsigned u[32];
#pragma unroll
    for (int k = 0; k < 32; k += 2) {
        const uint2 t2 = *(const uint2*)&qr[k];
        u[k] = t2.x; u[k + 1] = t2.y;
    }
    float S = 0.f;
#pragma unroll
    for (int k = 0; k < 32; ++k) {
        const float f0 = bflo(u[k]), f1 = bfhi(u[k]);
        S = fmaf(f0 * f0, rF[2 * k], S);
        S = fmaf(f1 * f1, rF[2 * k + 1], S);
    }
    const float rS = 1.f / S;
    const float lS = __logf(S);
    float acc = 0.f;
#pragma unroll
    for (int k = 0; k < 32; ++k) {
        const float f0 = bflo(u[k]), f1 = bfhi(u[k]);
        const float p0 = f0 * f0 * rF[2 * k] * rS;
        const float p1 = f1 * f1 * rF[2 * k + 1] * rS;
        acc += p0 * (__logf(f0) - lF[2 * k] - lS);
        acc += p1 * (__logf(f1) - lF[2 * k + 1] - lS);
    }
#pragma unroll
    for (int off = 32; off > 0; off >>= 1) acc += __shfl_down(acc, off, 64);
    if ((tid & 63) == 0) kred[tid >> 6] = acc;
    __syncthreads();
    if (tid == 0) atomicAdd(klacc, kred[0] + kred[1] + kred[2] + kred[3]);
}

__global__ __launch_bounds__(256) void k_ortho(
    const float* __restrict__ dict, float* __restrict__ oacc)
{
    __shared__ __align__(16) float dlds[CC * LDSS];
    const int tid = threadIdx.x;
    for (int idx = tid; idx < CC * DD; idx += 256)
        dlds[(idx >> 7) * LDSS + (idx & 127)] = dict[idx];
    __syncthreads();

    const int e = blockIdx.x * 256 + tid;
    const int i = e >> 6, jj = e & 63;
    const float* di = &dlds[i * LDSS];
    const float* dj = &dlds[jj * LDSS];
    float g = 0.f;
#pragma unroll 8
    for (int d = 0; d < DD; d += 4) {
        const float4 a = *(const float4*)(di + d);
        const float4 b = *(const float4*)(dj + d);
        g += a.x * b.x + a.y * b.y + a.z * b.z + a.w * b.w;
    }
    const float diff = g - ((i == jj) ? 1.f : 0.f);
    float v = diff * diff;
#pragma unroll
    for (int off = 32; off > 0; off >>= 1)
        v += __shfl_down(v, off, 64);
    if ((tid & 63) == 0) atomicAdd(oacc, v);
}

__global__ void k_final(const float* __restrict__ klacc,
                        const float* __restrict__ oacc,
                        float* __restrict__ out_scalar)
{
    out_scalar[0] = 0.5f * (klacc[0] / (float)ROWS) + 0.1f * (oacc[0] / 4096.f);
}

// ---------------------------------------------------------------------------
extern "C" void kernel_launch(void* const* d_in, const int* in_sizes, int n_in,
                              void* d_out, int out_size, void* d_ws, size_t ws_size,
                              hipStream_t stream)
{
    const float* x    = (const float*)d_in[0];   // (16, 8192, 128)
    const float* dict = (const float*)d_in[1];   // (64, 128)
    float* out = (float*)d_out;
    float* xcg = out;                               // (B,N,D)
    float* xrg = out + (size_t)ROWS * DD;           // (B,N,D)
    float* aux = out + 2 * (size_t)ROWS * DD;       // scalar

    float* ws      = (float*)d_ws;
    float* colsum  = ws;                 // 64 floats
    float* klacc   = ws + 64;            // 1
    float* oacc    = ws + 65;            // 1
    float* colpart = ws + 256;           // 1024*64 floats = 256 KB
    unsigned* qbuf = (unsigned*)(ws + 256 + 1024 * 64);  // fallback only

    void* kargs[9];
    kargs[0] = (void*)&x;
    kargs[1] = (void*)&dict;
    kargs[2] = (void*)&xcg;
    kargs[3] = (void*)&xrg;
    kargs[4] = (void*)&colpart;
    kargs[5] = (void*)&colsum;
    kargs[6] = (void*)&klacc;
    kargs[7] = (void*)&oacc;
    kargs[8] = (void*)&aux;

    hipError_t rc = hipLaunchCooperativeKernel((const void*)k_fused,
                                               dim3(ROWS / RPB), dim3(256),
                                               kargs, 0, stream);
    if (rc != hipSuccess) {
        // fallback: proven 5-kernel pipeline (round-1)
        hipMemsetAsync(d_ws, 0, 1024, stream);
        k_main  <<<ROWS / RPB, 256, 0, stream>>>(x, dict, xcg, xrg, qbuf, colpart);
        k_colsum<<<16,         256, 0, stream>>>(colpart, colsum);
        k_kl    <<<ROWS / 256, 256, 0, stream>>>(qbuf, colsum, klacc);
        k_ortho <<<16,         256, 0, stream>>>(dict, oacc);
        k_final <<<1,          1,   0, stream>>>(klacc, oacc, aux);
    }
}

// Round 3
// 388.582 us; speedup vs baseline: 1.3585x; 1.3585x over previous
//
#include <hip/hip_runtime.h>
#include <math.h>

#define BB 16
#define NN 8192
#define DD 128
#define CC 64
#define ROWS (BB*NN)            // 131072
#define INV_TEMP (1.0f/6.0f)    // temp = 2*(1+192/96) = 6
#define NEGF (-3.402823e38f)

#define RPB 128                 // rows per block
#define CHW 32                  // chunk width (floats of j)
#define XST 34                  // LDS row stride in dwords (2-way conflict max, 8B aligned)
#define GRID (ROWS / RPB)       // 1024 = 256 CU x 4 blocks/CU (co-resident; validated
                                // by round-2 cooperative launch at same resources)

__device__ __forceinline__ unsigned f2bf(float f) {
    unsigned u = __builtin_bit_cast(unsigned, f);
    return (u + 0x7fffu + ((u >> 16) & 1u)) >> 16;   // RNE
}
__device__ __forceinline__ float bflo(unsigned u) { return __builtin_bit_cast(float, u << 16); }
__device__ __forceinline__ float bfhi(unsigned u) { return __builtin_bit_cast(float, u & 0xffff0000u); }

// ===========================================================================
// k_all: whole pipeline, ONE kernel, ONE producer-signaled dependency.
//   A: scores/softmax/top4 (q stays in f32 regs), block colsum -> colpart
//   blocks 64..79: ortho gram term (dict L1-resident)
//   arrive cnt1 (ACQ_REL): LAST block reduces colpart -> colsum, releases flag
//   D: streaming xc/xr epilogue (hides the flag latency; warm caches)
//   spin flag (expected already set) -> KL from registers -> klacc
//   arrive cnt2: LAST block writes aux.
// No grid-wide barrier: no block ever idles waiting for stragglers.
// ===========================================================================
__global__ __launch_bounds__(256, 4) void k_all(
    const float* __restrict__ x, const float* __restrict__ dict,
    float* __restrict__ xcg, float* __restrict__ xrg,
    float* __restrict__ colpart, float* __restrict__ colsum,
    float* __restrict__ klacc, float* __restrict__ oacc,
    unsigned* __restrict__ cnt1, unsigned* __restrict__ flag,
    unsigned* __restrict__ cnt2, float* __restrict__ aux)
{
    __shared__ __align__(16) float bufA[RPB * XST];   // 17408 B: x stage, t4 exch, q bf16, rF/lF/kred, cred
    __shared__ float red2[RPB][2];
    __shared__ float colsumA[CC];
    __shared__ __align__(16) float w4s[RPB][4];       // top-4 softmax weights per row
    __shared__ __align__(16) int   si4s[RPB][4];      // top-4 indices per row
    __shared__ int lastA;

    const int tid   = threadIdx.x;
    const int rloc  = tid & (RPB - 1);
    const int chalf = tid >> 7;
    const int cbase = __builtin_amdgcn_readfirstlane(chalf << 5);  // wave-uniform -> s_load
    const int bid   = blockIdx.x;
    const int row0  = bid * RPB;

    if (tid < CC) colsumA[tid] = 0.f;

    const int sr = tid >> 3;            // staging row 0..31 (+32p)
    const int sj = (tid & 7) * 4;       // staging j offset
    const float* xstage = x + (size_t)(row0 + sr) * DD + sj;

    float s[32];
#pragma unroll
    for (int cc = 0; cc < 32; ++cc) s[cc] = 0.f;

    // ---------------- phase A1: scores, software-pipelined staging ---------
    float4 rp[4];
#pragma unroll
    for (int p = 0; p < 4; ++p)
        rp[p] = *(const float4*)(xstage + (size_t)p * 32 * DD);
#pragma unroll
    for (int p = 0; p < 4; ++p) {
        float* dst = &bufA[XST * (sr + 32 * p) + sj];
        *(float2*)dst       = make_float2(rp[p].x, rp[p].y);
        *(float2*)(dst + 2) = make_float2(rp[p].z, rp[p].w);
    }
    __syncthreads();

    for (int ch = 0; ch < 4; ++ch) {
        const int j0 = ch * CHW;
        if (ch < 3) {   // issue next chunk's loads; latency hides under compute
#pragma unroll
            for (int p = 0; p < 4; ++p)
                rp[p] = *(const float4*)(xstage + (size_t)p * 32 * DD + (j0 + CHW));
        }
        const float* xrow = &bufA[XST * rloc];
        for (int js = 0; js < CHW; js += 4) {
            const float2 x01 = *(const float2*)(xrow + js);
            const float2 x23 = *(const float2*)(xrow + js + 2);
            const float* dcol = dict + (size_t)cbase * DD + (j0 + js);
#pragma unroll
            for (int cc = 0; cc < 32; ++cc) {
                const float* dp = dcol + cc * DD;   // uniform address -> s_load
                float acc = s[cc];
                acc = fmaf(x01.x, dp[0], acc);
                acc = fmaf(x01.y, dp[1], acc);
                acc = fmaf(x23.x, dp[2], acc);
                acc = fmaf(x23.y, dp[3], acc);
                s[cc] = acc;
            }
        }
        if (ch < 3) {
            __syncthreads();   // all consumers of bufA done
#pragma unroll
            for (int p = 0; p < 4; ++p) {
                float* dst = &bufA[XST * (sr + 32 * p) + sj];
                *(float2*)dst       = make_float2(rp[p].x, rp[p].y);
                *(float2*)(dst + 2) = make_float2(rp[p].z, rp[p].w);
            }
            __syncthreads();
        }
    }

    // ---------------- phase A2: max across the pair ----------------
    float lm = s[0];
#pragma unroll
    for (int cc = 1; cc < 32; ++cc) lm = fmaxf(lm, s[cc]);
    red2[rloc][chalf] = lm;
    __syncthreads();
    const float mg = fmaxf(red2[rloc][0], red2[rloc][1]);
    __syncthreads();

    // ---------------- top-4 local on RAW s (strict '>' => lowest index) ----
    float tv[4]; int ti[4];
    {
        float best = NEGF; int bi = 0;
#pragma unroll
        for (int cc = 0; cc < 32; ++cc) { if (s[cc] > best) { best = s[cc]; bi = cc; } }
        tv[0] = best; ti[0] = bi;
    }
    {
        float best = NEGF; int bi = 0;
#pragma unroll
        for (int cc = 0; cc < 32; ++cc) {
            const float v = (cc == ti[0]) ? NEGF : s[cc];
            if (v > best) { best = v; bi = cc; }
        }
        tv[1] = best; ti[1] = bi;
    }
    {
        float best = NEGF; int bi = 0;
#pragma unroll
        for (int cc = 0; cc < 32; ++cc) {
            const float v = (cc == ti[0] || cc == ti[1]) ? NEGF : s[cc];
            if (v > best) { best = v; bi = cc; }
        }
        tv[2] = best; ti[2] = bi;
    }
    {
        float best = NEGF; int bi = 0;
#pragma unroll
        for (int cc = 0; cc < 32; ++cc) {
            const float v = (cc == ti[0] || cc == ti[1] || cc == ti[2]) ? NEGF : s[cc];
            if (v > best) { best = v; bi = cc; }
        }
        tv[3] = best; ti[3] = bi;
    }

    // ---------------- single exp pass: s -> e, then normalize to q ---------
    float lz = 0.f;
#pragma unroll
    for (int cc = 0; cc < 32; ++cc) {
        const float e = __expf((s[cc] - mg) * INV_TEMP);
        s[cc] = e; lz += e;
    }
    red2[rloc][chalf] = lz;
    __syncthreads();
    const float rZ = 1.f / (red2[rloc][0] + red2[rloc][1]);
#pragma unroll
    for (int cc = 0; cc < 32; ++cc) s[cc] *= rZ;     // s[] is now q (f32), live thru KL

    // ---------------- top-4 merge across the pair (via LDS) ---------------
    float* t4v = bufA;
    int*   t4i = (int*)(bufA + 1024);
    {
        const int b4 = (rloc * 2 + chalf) * 4;
#pragma unroll
        for (int k = 0; k < 4; ++k) { t4v[b4 + k] = tv[k]; t4i[b4 + k] = cbase + ti[k]; }
    }
    __syncthreads();
    float cv[8]; int ci[8];
#pragma unroll
    for (int h = 0; h < 2; ++h) {
#pragma unroll
        for (int k = 0; k < 4; ++k) {
            cv[h * 4 + k] = t4v[(rloc * 2 + h) * 4 + k];
            ci[h * 4 + k] = t4i[(rloc * 2 + h) * 4 + k];
        }
    }
    __syncthreads();   // bufA free for reuse after this

    int rank[8];
#pragma unroll
    for (int j = 0; j < 8; ++j) rank[j] = 0;
#pragma unroll
    for (int j = 0; j < 8; ++j) {
#pragma unroll
        for (int k = 0; k < 8; ++k) {
            if (k == j) continue;
            const bool kg = (cv[k] > cv[j]) || (cv[k] == cv[j] && ci[k] < ci[j]);
            rank[j] += kg ? 1 : 0;
        }
    }
    float sv[4]; int si[4];
#pragma unroll
    for (int t2 = 0; t2 < 4; ++t2) { sv[t2] = NEGF; si[t2] = 0; }
#pragma unroll
    for (int j = 0; j < 8; ++j) {
#pragma unroll
        for (int t2 = 0; t2 < 4; ++t2) {
            const bool sel = (rank[j] == t2);
            sv[t2] = sel ? cv[j] : sv[t2];
            si[t2] = sel ? ci[j] : si[t2];
        }
    }
    const float e1 = __expf((sv[1] - sv[0]) * INV_TEMP);
    const float e2 = __expf((sv[2] - sv[0]) * INV_TEMP);
    const float e3 = __expf((sv[3] - sv[0]) * INV_TEMP);
    const float rZ4 = 1.f / (1.f + e1 + e2 + e3);
    const float w0 = rZ4, w1 = e1 * rZ4, w2 = e2 * rZ4, w3 = e3 * rZ4;

    if (chalf == 0) {
        *(float4*)&w4s[rloc][0] = make_float4(w0, w1, w2, w3);
        *(int4*)&si4s[rloc][0]  = make_int4(si[0], si[1], si[2], si[3]);
    }

    // ---------------- q -> LDS (bf16) for conflict-free colsum only --------
    {
        unsigned* qs = (unsigned*)bufA;
        const int base = XST * rloc + 16 * chalf;
#pragma unroll
        for (int k2 = 0; k2 < 16; k2 += 2) {
            uint2 w;
            w.x = (f2bf(s[2 * k2 + 1]) << 16) | f2bf(s[2 * k2 + 0]);
            w.y = (f2bf(s[2 * k2 + 3]) << 16) | f2bf(s[2 * k2 + 2]);
            *(uint2*)&qs[base + k2] = w;
        }
        __syncthreads();
        const int cp  = tid & 31;
        const int rr0 = (tid >> 5) * 16;
        float c0 = 0.f, c1 = 0.f;
#pragma unroll
        for (int rr = 0; rr < 16; ++rr) {
            const unsigned u = qs[XST * (rr0 + rr) + cp];
            c0 += bflo(u); c1 += bfhi(u);
        }
        atomicAdd(&colsumA[2 * cp + 0], c0);   // 8-way only
        atomicAdd(&colsumA[2 * cp + 1], c1);
    }
    __syncthreads();
    if (tid < CC) colpart[bid * CC + tid] = colsumA[tid];

    // ---------------- ortho gram term (blocks 64..79, dict L1-resident) ----
    if (bid >= 64 && bid < 80) {
        const int e = (bid - 64) * 256 + tid;   // [0,4096)
        const int i = e >> 6, jj = e & 63;
        const float* di = dict + (size_t)i * DD;
        const float* dj = dict + (size_t)jj * DD;
        float g = 0.f;
#pragma unroll 8
        for (int d = 0; d < DD; d += 4) {
            const float4 a = *(const float4*)(di + d);
            const float4 b = *(const float4*)(dj + d);
            g += a.x * b.x + a.y * b.y + a.z * b.z + a.w * b.w;
        }
        const float diff = g - ((i == jj) ? 1.f : 0.f);
        float v = diff * diff;
#pragma unroll
        for (int off = 32; off > 0; off >>= 1)
            v += __shfl_down(v, off, 64);
        if ((tid & 63) == 0) atomicAdd(oacc, v);
    }

    // ---------------- arrive; LAST block reduces colpart -> colsum ---------
    __syncthreads();   // colpart stores drained (vmcnt(0) before barrier)
    if (tid == 0) {
        const unsigned prev = __hip_atomic_fetch_add(
            cnt1, 1u, __ATOMIC_ACQ_REL, __HIP_MEMORY_SCOPE_AGENT);
        lastA = (prev == (unsigned)(GRID - 1)) ? 1 : 0;
    }
    __syncthreads();
    if (lastA) {
        const int c = tid & 63, qt = tid >> 6;
        float v = 0.f;
#pragma unroll 8
        for (int i = 0; i < 256; ++i)
            v += colpart[(size_t)(((qt << 8) + i) * 64 + c)];   // coalesced, L2/L3-hot
        float* cred = bufA;
        cred[tid] = v;
        __syncthreads();
        if (tid < CC)
            __hip_atomic_store(&colsum[tid],
                cred[tid] + cred[tid + 64] + cred[tid + 128] + cred[tid + 192],
                __ATOMIC_RELAXED, __HIP_MEMORY_SCOPE_AGENT);
        __syncthreads();   // colsum stores drained
        if (tid == 0)
            __hip_atomic_store(flag, 1u, __ATOMIC_RELEASE, __HIP_MEMORY_SCOPE_AGENT);
    }

    // ---------------- phase D: streaming epilogue (hides flag latency) -----
#pragma unroll 2
    for (int it = 0; it < 16; ++it) {
        const int gd  = it * 1024 + tid * 4;
        const int row = gd >> 7;
        const int dd  = gd & 127;
        const float4 wv = *(const float4*)&w4s[row][0];
        const int4  iv  = *(const int4*)&si4s[row][0];
        const size_t go = (size_t)(row0 + row) * DD + dd;
        const float4 xv = *(const float4*)(x + go);
        const float4 d0 = *(const float4*)(dict + (size_t)iv.x * DD + dd);
        const float4 d1 = *(const float4*)(dict + (size_t)iv.y * DD + dd);
        const float4 d2 = *(const float4*)(dict + (size_t)iv.z * DD + dd);
        const float4 d3 = *(const float4*)(dict + (size_t)iv.w * DD + dd);
        float4 c4, r4;
        c4.x = fmaf(wv.w, d3.x, fmaf(wv.z, d2.x, fmaf(wv.y, d1.x, wv.x * d0.x)));
        c4.y = fmaf(wv.w, d3.y, fmaf(wv.z, d2.y, fmaf(wv.y, d1.y, wv.x * d0.y)));
        c4.z = fmaf(wv.w, d3.z, fmaf(wv.z, d2.z, fmaf(wv.y, d1.z, wv.x * d0.z)));
        c4.w = fmaf(wv.w, d3.w, fmaf(wv.z, d2.w, fmaf(wv.y, d1.w, wv.x * d0.w)));
        r4.x = xv.x - c4.x; r4.y = xv.y - c4.y;
        r4.z = xv.z - c4.z; r4.w = xv.w - c4.w;
        *(float4*)(xcg + go) = c4;
        *(float4*)(xrg + go) = r4;
    }

    // ---------------- wait for colsum (expected: already set) --------------
    if (tid == 0) {
        while (__hip_atomic_load(flag, __ATOMIC_ACQUIRE, __HIP_MEMORY_SCOPE_AGENT) == 0u)
            __builtin_amdgcn_s_sleep(8);
    }
    __syncthreads();

    // ---------------- KL from f32 q in registers ---------------------------
    {
        float* rF   = bufA;         // 64
        float* lF   = bufA + 64;    // 64
        float* kred = bufA + 128;   // 4
        if (tid < CC) {
            const float F = __hip_atomic_load(&colsum[tid],
                __ATOMIC_RELAXED, __HIP_MEMORY_SCOPE_AGENT);
            rF[tid] = 1.f / F; lF[tid] = __logf(F);
        }
        __syncthreads();
        float Sh = 0.f;
#pragma unroll
        for (int cc = 0; cc < 32; ++cc) Sh = fmaf(s[cc] * s[cc], rF[cbase + cc], Sh);
        red2[rloc][chalf] = Sh;
        __syncthreads();
        const float Sr = red2[rloc][0] + red2[rloc][1];
        const float rS = 1.f / Sr;
        const float lS = __logf(Sr);
        float acc = 0.f;
#pragma unroll
        for (int cc = 0; cc < 32; ++cc) {
            const float q = s[cc];
            const float p = q * q * rF[cbase + cc] * rS;
            acc += p * (__logf(q) - lF[cbase + cc] - lS);
        }
#pragma unroll
        for (int off = 32; off > 0; off >>= 1) acc += __shfl_down(acc, off, 64);
        if ((tid & 63) == 0) kred[tid >> 6] = acc;
        __syncthreads();
        if (tid == 0) {
            atomicAdd(klacc, kred[0] + kred[1] + kred[2] + kred[3]);
            // arrive #2: LAST block writes aux (release in fetch_add orders
            // this block's klacc add before its cnt2 increment; acquire lets
            // the last block see all others' adds).
            const unsigned prev = __hip_atomic_fetch_add(
                cnt2, 1u, __ATOMIC_ACQ_REL, __HIP_MEMORY_SCOPE_AGENT);
            if (prev == (unsigned)(GRID - 1)) {
                const float kt = __hip_atomic_load(klacc,
                    __ATOMIC_RELAXED, __HIP_MEMORY_SCOPE_AGENT);
                const float ot = __hip_atomic_load(oacc,
                    __ATOMIC_RELAXED, __HIP_MEMORY_SCOPE_AGENT);
                aux[0] = 0.5f * (kt / (float)ROWS) + 0.1f * (ot / 4096.f);
            }
        }
    }
}

// ---------------------------------------------------------------------------
extern "C" void kernel_launch(void* const* d_in, const int* in_sizes, int n_in,
                              void* d_out, int out_size, void* d_ws, size_t ws_size,
                              hipStream_t stream)
{
    const float* x    = (const float*)d_in[0];   // (16, 8192, 128)
    const float* dict = (const float*)d_in[1];   // (64, 128)
    float* out = (float*)d_out;
    float* xcg = out;                               // (B,N,D)
    float* xrg = out + (size_t)ROWS * DD;           // (B,N,D)
    float* aux = out + 2 * (size_t)ROWS * DD;       // scalar

    float* ws       = (float*)d_ws;
    float* colsum   = ws;                 // 64 floats
    float* klacc    = ws + 64;            // 1
    float* oacc     = ws + 65;            // 1
    unsigned* cnt1  = (unsigned*)(ws + 66);
    unsigned* flag  = (unsigned*)(ws + 67);
    unsigned* cnt2  = (unsigned*)(ws + 68);
    float* colpart  = ws + 256;           // 1024*64 floats = 256 KB

    hipMemsetAsync(d_ws, 0, 1024, stream);   // zeros colsum/klacc/oacc/cnt1/flag/cnt2

    k_all<<<GRID, 256, 0, stream>>>(x, dict, xcg, xrg, colpart, colsum,
                                    klacc, oacc, cnt1, flag, cnt2, aux);
}

// Round 4
// 280.510 us; speedup vs baseline: 1.8819x; 1.3853x over previous
//
#include <hip/hip_runtime.h>
#include <math.h>

#define BB 16
#define NN 8192
#define DD 128
#define CC 64
#define ROWS (BB*NN)            // 131072
#define INV_TEMP (1.0f/6.0f)    // temp = 2*(1+192/96) = 6
#define NEGF (-3.402823e38f)

#define RPB 64                  // rows per block (4 threads/row)
#define CHW 32                  // chunk width (floats of j)
#define XST 34                  // LDS row stride in dwords (2-way conflict max, 8B aligned)
#define GRIDM (ROWS / RPB)      // 2048 blocks = 256 CU x 8 blocks/CU

__device__ __forceinline__ unsigned f2bf(float f) {
    unsigned u = __builtin_bit_cast(unsigned, f);
    return (u + 0x7fffu + ((u >> 16) & 1u)) >> 16;   // RNE
}
__device__ __forceinline__ float bflo(unsigned u) { return __builtin_bit_cast(float, u << 16); }
__device__ __forceinline__ float bfhi(unsigned u) { return __builtin_bit_cast(float, u & 0xffff0000u); }

// ---------------------------------------------------------------------------
// k_main: 4 threads per row (c-quarters; wave w handles c 16w..16w+15 so the
// dict pointer stays wave-uniform -> s_load). RPB=64, grid 2048,
// launch_bounds(256,8) -> up to 32 waves/CU (2x round-1) for latency hiding.
// LDS 20224 B <= 20480 (160K/8). Candidate exchange in m-major t4[16][64]
// (stride-1 lanes, conflict-free). Merge runs after q-pack so cv/ci reuse
// the dead s[] registers.
// ---------------------------------------------------------------------------
__global__ __launch_bounds__(256, 8) void k_main(
    const float* __restrict__ x, const float* __restrict__ dict,
    float* __restrict__ xcg, float* __restrict__ xrg,
    unsigned* __restrict__ qg, float* __restrict__ colpart)
{
    __shared__ __align__(16) float bufA[RPB * XST];      // 8704 B: x stage, then q bf16
    __shared__ __align__(16) float t4v[16][RPB];         // 4096 B  (m-major)
    __shared__ __align__(16) int   t4i[16][RPB];         // 4096 B
    __shared__ float red4[RPB][4];                       // 1024 B
    __shared__ float colsumA[CC];                        // 256 B
    __shared__ __align__(16) float w4s[RPB][4];          // 1024 B
    __shared__ __align__(16) int   si4s[RPB][4];         // 1024 B

    const int tid   = threadIdx.x;
    const int rloc  = tid & (RPB - 1);
    const int qh    = tid >> 6;                              // wave id = c-quarter
    const int cbase = __builtin_amdgcn_readfirstlane(qh << 4);
    const int row0  = blockIdx.x * RPB;

    if (tid < CC) colsumA[tid] = 0.f;

    const int sr = tid >> 3;            // staging row 0..31 (+32p)
    const int sj = (tid & 7) * 4;       // staging j offset
    const float* xstage = x + (size_t)(row0 + sr) * DD + sj;

    float s[16];
#pragma unroll
    for (int cc = 0; cc < 16; ++cc) s[cc] = 0.f;

    // ---------------- phase 1: scores, software-pipelined staging ----------
    float4 rp[2];
#pragma unroll
    for (int p = 0; p < 2; ++p)
        rp[p] = *(const float4*)(xstage + (size_t)p * 32 * DD);
#pragma unroll
    for (int p = 0; p < 2; ++p) {
        float* dst = &bufA[XST * (sr + 32 * p) + sj];
        *(float2*)dst       = make_float2(rp[p].x, rp[p].y);
        *(float2*)(dst + 2) = make_float2(rp[p].z, rp[p].w);
    }
    __syncthreads();

    for (int ch = 0; ch < 4; ++ch) {
        const int j0 = ch * CHW;
        if (ch < 3) {   // next chunk's loads issue under compute
#pragma unroll
            for (int p = 0; p < 2; ++p)
                rp[p] = *(const float4*)(xstage + (size_t)p * 32 * DD + (j0 + CHW));
        }
        const float* xrow = &bufA[XST * rloc];
        for (int js = 0; js < CHW; js += 4) {
            const float2 x01 = *(const float2*)(xrow + js);
            const float2 x23 = *(const float2*)(xrow + js + 2);
            const float* dcol = dict + (size_t)cbase * DD + (j0 + js);
#pragma unroll
            for (int cc = 0; cc < 16; ++cc) {
                const float* dp = dcol + cc * DD;   // wave-uniform -> s_load
                float acc = s[cc];
                acc = fmaf(x01.x, dp[0], acc);
                acc = fmaf(x01.y, dp[1], acc);
                acc = fmaf(x23.x, dp[2], acc);
                acc = fmaf(x23.y, dp[3], acc);
                s[cc] = acc;
            }
        }
        if (ch < 3) {
            __syncthreads();   // all consumers of bufA done
#pragma unroll
            for (int p = 0; p < 2; ++p) {
                float* dst = &bufA[XST * (sr + 32 * p) + sj];
                *(float2*)dst       = make_float2(rp[p].x, rp[p].y);
                *(float2*)(dst + 2) = make_float2(rp[p].z, rp[p].w);
            }
            __syncthreads();
        }
    }

    // ---------------- phase 2: max across the 4 quarters ----------------
    float lm = s[0];
#pragma unroll
    for (int cc = 1; cc < 16; ++cc) lm = fmaxf(lm, s[cc]);
    red4[rloc][qh] = lm;
    __syncthreads();
    const float mg = fmaxf(fmaxf(red4[rloc][0], red4[rloc][1]),
                           fmaxf(red4[rloc][2], red4[rloc][3]));

    // ---------------- top-4 local on RAW s (strict '>' => lowest index) ----
    float tv[4]; int ti[4];
    {
        float best = NEGF; int bi = 0;
#pragma unroll
        for (int cc = 0; cc < 16; ++cc) { if (s[cc] > best) { best = s[cc]; bi = cc; } }
        tv[0] = best; ti[0] = bi;
    }
    {
        float best = NEGF; int bi = 0;
#pragma unroll
        for (int cc = 0; cc < 16; ++cc) {
            const float v = (cc == ti[0]) ? NEGF : s[cc];
            if (v > best) { best = v; bi = cc; }
        }
        tv[1] = best; ti[1] = bi;
    }
    {
        float best = NEGF; int bi = 0;
#pragma unroll
        for (int cc = 0; cc < 16; ++cc) {
            const float v = (cc == ti[0] || cc == ti[1]) ? NEGF : s[cc];
            if (v > best) { best = v; bi = cc; }
        }
        tv[2] = best; ti[2] = bi;
    }
    {
        float best = NEGF; int bi = 0;
#pragma unroll
        for (int cc = 0; cc < 16; ++cc) {
            const float v = (cc == ti[0] || cc == ti[1] || cc == ti[2]) ? NEGF : s[cc];
            if (v > best) { best = v; bi = cc; }
        }
        tv[3] = best; ti[3] = bi;
    }

    // ---------------- single exp pass: s -> e, then normalize to q ---------
    float lz = 0.f;
#pragma unroll
    for (int cc = 0; cc < 16; ++cc) {
        const float e = __expf((s[cc] - mg) * INV_TEMP);
        s[cc] = e; lz += e;
    }
    __syncthreads();   // all mg reads done before red4 rewrite
    red4[rloc][qh] = lz;
    __syncthreads();
    const float rZ = 1.f / (red4[rloc][0] + red4[rloc][1] + red4[rloc][2] + red4[rloc][3]);
#pragma unroll
    for (int cc = 0; cc < 16; ++cc) s[cc] *= rZ;     // s[] is now q

    // ---------------- publish candidates (m-major, stride-1 lanes) ---------
#pragma unroll
    for (int k = 0; k < 4; ++k) {
        t4v[qh * 4 + k][rloc] = tv[k];
        t4i[qh * 4 + k][rloc] = cbase + ti[k];
    }

    // ---------------- q -> LDS (bf16); s[] dead after this -----------------
    unsigned* qs = (unsigned*)bufA;
    {
        const int base = XST * rloc + 8 * qh;
#pragma unroll
        for (int k2 = 0; k2 < 8; k2 += 2) {
            uint2 w;
            w.x = (f2bf(s[2 * k2 + 1]) << 16) | f2bf(s[2 * k2 + 0]);
            w.y = (f2bf(s[2 * k2 + 3]) << 16) | f2bf(s[2 * k2 + 2]);
            *(uint2*)&qs[base + k2] = w;
        }
    }
    __syncthreads();   // qs + t4 visible

    // ---------------- colsum partials (conflict-free reads, 8-way atomics) -
    {
        const int cp  = tid & 31;           // column pair (dword index)
        const int rr0 = (tid >> 5) * 8;     // 8 rows per thread-group
        float c0 = 0.f, c1 = 0.f;
#pragma unroll
        for (int rr = 0; rr < 8; ++rr) {
            const unsigned u = qs[XST * (rr0 + rr) + cp];
            c0 += bflo(u); c1 += bfhi(u);
        }
        atomicAdd(&colsumA[2 * cp + 0], c0);
        atomicAdd(&colsumA[2 * cp + 1], c1);
    }

    // ---------------- q -> global (coalesced) ------------------------------
    {
        unsigned* qdst = qg + (size_t)blockIdx.x * (RPB * 32);
#pragma unroll
        for (int k4 = 0; k4 < 2; ++k4) {
            const int gd  = k4 * 1024 + tid * 4;
            const int row = gd >> 5, kk = gd & 31;
            const uint2 a = *(const uint2*)&qs[XST * row + kk];
            const uint2 b = *(const uint2*)&qs[XST * row + kk + 2];
            uint4 o; o.x = a.x; o.y = a.y; o.z = b.x; o.w = b.y;
            *(uint4*)&qdst[gd] = o;
        }
    }

    // ---------------- merge 16 candidates (value desc, index asc) ----------
    {
        float cv[16]; int ci[16];
#pragma unroll
        for (int m = 0; m < 16; ++m) { cv[m] = t4v[m][rloc]; ci[m] = t4i[m][rloc]; }
        float sv[4]; int si[4];
#pragma unroll
        for (int t = 0; t < 4; ++t) {
            float best = NEGF; int bi = 1 << 30;
#pragma unroll
            for (int m = 0; m < 16; ++m) {
                bool used = false;
#pragma unroll
                for (int u2 = 0; u2 < 3; ++u2)
                    if (u2 < t) used = used || (ci[m] == si[u2]);
                const bool better = !used &&
                    (cv[m] > best || (cv[m] == best && ci[m] < bi));
                best = better ? cv[m] : best;
                bi   = better ? ci[m] : bi;
            }
            sv[t] = best; si[t] = bi;
        }
        const float e1 = __expf((sv[1] - sv[0]) * INV_TEMP);
        const float e2 = __expf((sv[2] - sv[0]) * INV_TEMP);
        const float e3 = __expf((sv[3] - sv[0]) * INV_TEMP);
        const float rZ4 = 1.f / (1.f + e1 + e2 + e3);
        if (qh == 0) {
            *(float4*)&w4s[rloc][0] = make_float4(rZ4, e1 * rZ4, e2 * rZ4, e3 * rZ4);
            *(int4*)&si4s[rloc][0]  = make_int4(si[0], si[1], si[2], si[3]);
        }
    }
    __syncthreads();   // w4s/si4s visible; colsumA atomics done
    if (tid < CC) colpart[blockIdx.x * CC + tid] = colsumA[tid];

    // ---------------- phase 3: barrier-free streaming epilogue -------------
#pragma unroll 2
    for (int it = 0; it < 8; ++it) {
        const int gd  = it * 1024 + tid * 4;
        const int row = gd >> 7;
        const int dd  = gd & 127;
        const float4 wv = *(const float4*)&w4s[row][0];
        const int4  iv  = *(const int4*)&si4s[row][0];
        const size_t go = (size_t)(row0 + row) * DD + dd;
        const float4 xv = *(const float4*)(x + go);
        const float4 d0 = *(const float4*)(dict + (size_t)iv.x * DD + dd);
        const float4 d1 = *(const float4*)(dict + (size_t)iv.y * DD + dd);
        const float4 d2 = *(const float4*)(dict + (size_t)iv.z * DD + dd);
        const float4 d3 = *(const float4*)(dict + (size_t)iv.w * DD + dd);
        float4 c4, r4;
        c4.x = fmaf(wv.w, d3.x, fmaf(wv.z, d2.x, fmaf(wv.y, d1.x, wv.x * d0.x)));
        c4.y = fmaf(wv.w, d3.y, fmaf(wv.z, d2.y, fmaf(wv.y, d1.y, wv.x * d0.y)));
        c4.z = fmaf(wv.w, d3.z, fmaf(wv.z, d2.z, fmaf(wv.y, d1.z, wv.x * d0.z)));
        c4.w = fmaf(wv.w, d3.w, fmaf(wv.z, d2.w, fmaf(wv.y, d1.w, wv.x * d0.w)));
        r4.x = xv.x - c4.x; r4.y = xv.y - c4.y;
        r4.z = xv.z - c4.z; r4.w = xv.w - c4.w;
        *(float4*)(xcg + go) = c4;
        *(float4*)(xrg + go) = r4;
    }
}

// ---------------------------------------------------------------------------
// k_tail: blocks 0..15 reduce colpart[2048][64] -> colsum[64];
//         blocks 16..31 compute the ortho gram term (dict L2-resident).
// ---------------------------------------------------------------------------
__global__ __launch_bounds__(256) void k_tail(
    const float* __restrict__ colpart, float* __restrict__ colsum,
    const float* __restrict__ dict, float* __restrict__ oacc)
{
    const int tid = threadIdx.x;
    if (blockIdx.x < 16) {
        const int c   = tid & 63;
        const int seg = blockIdx.x * 4 + (tid >> 6);   // 0..63
        float v = 0.f;
#pragma unroll 8
        for (int b = 0; b < 32; ++b)
            v += colpart[(size_t)((seg * 32 + b) * 64 + c)];
        atomicAdd(&colsum[c], v);
    } else {
        const int e = (blockIdx.x - 16) * 256 + tid;   // [0,4096)
        const int i = e >> 6, jj = e & 63;
        const float* di = dict + (size_t)i * DD;
        const float* dj = dict + (size_t)jj * DD;
        float g = 0.f;
#pragma unroll 8
        for (int d = 0; d < DD; d += 4) {
            const float4 a = *(const float4*)(di + d);
            const float4 b = *(const float4*)(dj + d);
            g += a.x * b.x + a.y * b.y + a.z * b.z + a.w * b.w;
        }
        const float diff = g - ((i == jj) ? 1.f : 0.f);
        float v = diff * diff;
#pragma unroll
        for (int off = 32; off > 0; off >>= 1)
            v += __shfl_down(v, off, 64);
        if ((tid & 63) == 0) atomicAdd(oacc, v);
    }
}

// ---------------------------------------------------------------------------
// k_kl: per-row KL from bf16 q; LAST block (arrive counter) writes aux.
// ---------------------------------------------------------------------------
__global__ __launch_bounds__(256, 2) void k_kl(
    const unsigned* __restrict__ qg, const float* __restrict__ colsum,
    float* __restrict__ klacc, const float* __restrict__ oacc,
    unsigned* __restrict__ cnt, float* __restrict__ aux)
{
    __shared__ __align__(8) unsigned qs[256 * XST];  // 34816 B
    __shared__ float rF[CC], lF[CC];
    __shared__ float kred[4];
    const int tid = threadIdx.x;
    if (tid < CC) { const float F = colsum[tid]; rF[tid] = 1.f / F; lF[tid] = __logf(F); }
    const unsigned* qb = qg + (size_t)blockIdx.x * 8192;
#pragma unroll
    for (int g = 0; g < 8; ++g) {
        const int gd = g * 1024 + tid * 4;
        const uint4 v = *(const uint4*)(qb + gd);
        const int row = gd >> 5, kk = gd & 31;
        *(uint2*)&qs[XST * row + kk]     = make_uint2(v.x, v.y);
        *(uint2*)&qs[XST * row + kk + 2] = make_uint2(v.z, v.w);
    }
    __syncthreads();
    const unsigned* qr = &qs[XST * tid];
    unsigned u[32];
#pragma unroll
    for (int k = 0; k < 32; k += 2) {
        const uint2 t2 = *(const uint2*)&qr[k];
        u[k] = t2.x; u[k + 1] = t2.y;
    }
    float S = 0.f;
#pragma unroll
    for (int k = 0; k < 32; ++k) {
        const float f0 = bflo(u[k]), f1 = bfhi(u[k]);
        S = fmaf(f0 * f0, rF[2 * k], S);
        S = fmaf(f1 * f1, rF[2 * k + 1], S);
    }
    const float rS = 1.f / S;
    const float lS = __logf(S);
    float acc = 0.f;
#pragma unroll
    for (int k = 0; k < 32; ++k) {
        const float f0 = bflo(u[k]), f1 = bfhi(u[k]);
        const float p0 = f0 * f0 * rF[2 * k] * rS;
        const float p1 = f1 * f1 * rF[2 * k + 1] * rS;
        acc += p0 * (__logf(f0) - lF[2 * k] - lS);
        acc += p1 * (__logf(f1) - lF[2 * k + 1] - lS);
    }
#pragma unroll
    for (int off = 32; off > 0; off >>= 1) acc += __shfl_down(acc, off, 64);
    if ((tid & 63) == 0) kred[tid >> 6] = acc;
    __syncthreads();
    if (tid == 0) {
        atomicAdd(klacc, kred[0] + kred[1] + kred[2] + kred[3]);
        // arrive: release orders our klacc add before the increment; the last
        // block's acquire sees all prior adds (atomics at device coherence pt).
        const unsigned prev = __hip_atomic_fetch_add(
            cnt, 1u, __ATOMIC_ACQ_REL, __HIP_MEMORY_SCOPE_AGENT);
        if (prev == (unsigned)(ROWS / 256 - 1)) {
            const float kt = __hip_atomic_load(klacc,
                __ATOMIC_RELAXED, __HIP_MEMORY_SCOPE_AGENT);
            const float ot = __hip_atomic_load((float*)oacc,
                __ATOMIC_RELAXED, __HIP_MEMORY_SCOPE_AGENT);
            aux[0] = 0.5f * (kt / (float)ROWS) + 0.1f * (ot / 4096.f);
        }
    }
}

// ---------------------------------------------------------------------------
extern "C" void kernel_launch(void* const* d_in, const int* in_sizes, int n_in,
                              void* d_out, int out_size, void* d_ws, size_t ws_size,
                              hipStream_t stream)
{
    const float* x    = (const float*)d_in[0];   // (16, 8192, 128)
    const float* dict = (const float*)d_in[1];   // (64, 128)
    float* out = (float*)d_out;
    float* xcg = out;                               // (B,N,D)
    float* xrg = out + (size_t)ROWS * DD;           // (B,N,D)
    float* aux = out + 2 * (size_t)ROWS * DD;       // scalar

    float* ws       = (float*)d_ws;
    float* colsum   = ws;                 // 64 floats
    float* klacc    = ws + 64;            // 1
    float* oacc     = ws + 65;            // 1
    unsigned* cnt   = (unsigned*)(ws + 66);
    float* colpart  = ws + 256;                       // 2048*64 floats = 512 KB
    unsigned* qbuf  = (unsigned*)(ws + 256 + GRIDM * CC);  // 16.75 MB

    hipMemsetAsync(d_ws, 0, 1024, stream);   // zeros colsum/klacc/oacc/cnt

    k_main<<<GRIDM,      256, 0, stream>>>(x, dict, xcg, xrg, qbuf, colpart);
    k_tail<<<32,         256, 0, stream>>>(colpart, colsum, dict, oacc);
    k_kl  <<<ROWS / 256, 256, 0, stream>>>(qbuf, colsum, klacc, oacc, cnt, aux);
}